// Round 5
// baseline (1633.177 us; speedup 1.0000x reference)
//
#include <hip/hip_runtime.h>
#include <math.h>
#include <stdint.h>

// Problem constants (from reference): N=8192, F=256, HID=128, C=64
#define NROWS 8192
#define EDGE_CAP 128   // max row degree ~70 (Binomial(8192,0.005)); 128 is safe

// ============================================================================
// DIAGNOSTIC ROUND v2 (per-dispatch amplification): each BLOCK repeats its own
// idempotent work inside ONE dispatch — K1 x8, phases x16 — so every kernel's
// single-dispatch duration exceeds the 161 us harness fills and surfaces in
// the rocprof top-5 WITH counters. True cost = row_dur / REP.
// asm-"memory" per rep prevents cross-rep hoisting/CSE of loads.
// dur_us will be ~1.7 ms this round by design.
// ============================================================================
#define REP_K1 8
#define REP_PH 16

using f4v   = __attribute__((ext_vector_type(4))) float;
using u16x4 = __attribute__((ext_vector_type(4))) uint16_t;

// bf16 helpers (RNE pack, shift unpack); values are finite here.
__device__ __forceinline__ uint16_t bfpack(float f) {
    uint32_t x = __float_as_uint(f);
    return (uint16_t)((x + 0x7FFFu + ((x >> 16) & 1u)) >> 16);
}
__device__ __forceinline__ float bfun(uint16_t u) {
    return __uint_as_float((uint32_t)u << 16);
}

// ---------------------------------------------------------------------------
// K1 (fused, heterogeneous): blocks [0,256)   : Y|Z = feat @ [W0_top || W0_bot]
//                            blocks [256,2304): dense adj -> fixed-stride CSR
// ---------------------------------------------------------------------------
__global__ __launch_bounds__(256) void fused_csr_gemm1(const float* __restrict__ adj,
                                                       int* __restrict__ cnt,
                                                       int* __restrict__ col,
                                                       const float* __restrict__ A,
                                                       const float* __restrict__ W,
                                                       float* __restrict__ Y,
                                                       float* __restrict__ Z) {
    __shared__ float As[16][64];     // 4 KB
    __shared__ float Bs[16][128];    // 8 KB
    int gb  = blockIdx.x;
    int tid = threadIdx.x;

    for (int rep = 0; rep < REP_K1; ++rep) {
        asm volatile("" ::: "memory");   // no cross-rep CSE/hoist
        if (gb < 256) {
            // ---- GEMM role: BM=64, BN=128, K=256; 4x8 per thread ----
            int bm = gb & 127, bn = gb >> 7;          // bn=0 -> Y, bn=1 -> Z
            int tx = tid & 15, ty = tid >> 4;
            const float* Wb = W + (size_t)bn * 256 * 128;
            float acc[4][8] = {};
            for (int k0 = 0; k0 < 256; k0 += 16) {
                {   // A tile 64x16
                    int r = tid >> 2, kk = (tid & 3) * 4;
                    float4 v = *(const float4*)&A[(size_t)(bm * 64 + r) * 256 + k0 + kk];
                    As[kk + 0][r] = v.x; As[kk + 1][r] = v.y;
                    As[kk + 2][r] = v.z; As[kk + 3][r] = v.w;
                }
                {   // B tile 16x128
                    int kk = tid >> 4, c = (tid & 15) * 8;
                    *(float4*)&Bs[kk][c]     = *(const float4*)&Wb[(size_t)(k0 + kk) * 128 + c];
                    *(float4*)&Bs[kk][c + 4] = *(const float4*)&Wb[(size_t)(k0 + kk) * 128 + c + 4];
                }
                __syncthreads();
                #pragma unroll
                for (int kk = 0; kk < 16; ++kk) {
                    float a[4], b[8];
                    #pragma unroll
                    for (int i = 0; i < 4; ++i) a[i] = As[kk][ty * 4 + i];
                    #pragma unroll
                    for (int j = 0; j < 8; ++j) b[j] = Bs[kk][tx * 8 + j];
                    #pragma unroll
                    for (int i = 0; i < 4; ++i)
                        #pragma unroll
                        for (int j = 0; j < 8; ++j) acc[i][j] += a[i] * b[j];
                }
                __syncthreads();    // also protects next rep's As/Bs overwrite
            }
            float* O = bn ? Z : Y;
            #pragma unroll
            for (int i = 0; i < 4; ++i) {
                int r = bm * 64 + ty * 4 + i;
                float4 v0 = {acc[i][0], acc[i][1], acc[i][2], acc[i][3]};
                float4 v1 = {acc[i][4], acc[i][5], acc[i][6], acc[i][7]};
                *(float4*)&O[(size_t)r * 128 + tx * 8]     = v0;
                *(float4*)&O[(size_t)r * 128 + tx * 8 + 4] = v1;
            }
        } else {
            // ---- CSR role: wave per row, ballot compaction ----
            int row  = (gb - 256) * 4 + (tid >> 6);
            int lane = tid & 63;
            const f4v* arow = (const f4v*)(adj + (size_t)row * NROWS);
            int* crow = col + (size_t)row * EDGE_CAP;
            int count = 0;
            for (int it = 0; it < NROWS / 256; ++it) {   // 32 iters: 64 lanes x float4
                f4v v = __builtin_nontemporal_load(&arow[it * 64 + lane]);
                float vv[4] = {v.x, v.y, v.z, v.w};
                #pragma unroll
                for (int p = 0; p < 4; ++p) {
                    bool nz = vv[p] > 0.0f;
                    unsigned long long m = __ballot(nz);
                    if (nz) {
                        int off = count + __popcll(m & ((1ull << lane) - 1ull));
                        if (off < EDGE_CAP) crow[off] = it * 256 + lane * 4 + p;
                    }
                    count += __popcll(m);   // wave-uniform
                }
            }
            if (lane == 0) cnt[row] = count < EDGE_CAP ? count : EDGE_CAP;
        }
    }
}

// ---------------------------------------------------------------------------
// K2 (phase B): H1[i,:] = sum_j Y1[j,:] + Z1[i,:]; src1/dst1 dots fused.
// ---------------------------------------------------------------------------
__global__ __launch_bounds__(256) void k_phaseB(const int* __restrict__ cnt,
                                                const int* __restrict__ col,
                                                const float* __restrict__ Y1,
                                                const float* __restrict__ Z1,
                                                const float* __restrict__ a0,
                                                float* __restrict__ H1,
                                                float* __restrict__ src1,
                                                float* __restrict__ dst1) {
    __shared__ int elist[4][EDGE_CAP];
    const int wav  = threadIdx.x >> 6;
    const int lane = threadIdx.x & 63;
    const int row  = blockIdx.x * 4 + wav;

    for (int rep = 0; rep < REP_PH; ++rep) {
        asm volatile("" ::: "memory");
        const int n   = cnt[row];
        const int* cr = col + (size_t)row * EDGE_CAP;
        int* el = elist[wav];
        for (int e = lane; e < n; e += 64) el[e] = cr[e];

        const int half = lane >> 5, sub = lane & 31;   // 2 edges per instruction
        const float4* Y4 = (const float4*)Y1;          // row = 32 float4
        float4 s = {0.0f, 0.0f, 0.0f, 0.0f};
        int e = 0;
        for (; e + 16 <= n; e += 16) {                 // 8 instrs = 16 edges in flight
            float4 v[8];
            #pragma unroll
            for (int u = 0; u < 8; ++u) {
                int j = el[e + 2 * u + half];
                v[u] = Y4[(size_t)j * 32 + sub];
            }
            #pragma unroll
            for (int u = 0; u < 8; ++u) {
                s.x += v[u].x; s.y += v[u].y; s.z += v[u].z; s.w += v[u].w;
            }
        }
        for (; e < n; e += 2) {
            int idx = e + half;
            int j = el[idx < n ? idx : n - 1];         // clamped safe address
            float4 v = Y4[(size_t)j * 32 + sub];
            if (idx < n) { s.x += v.x; s.y += v.y; s.z += v.z; s.w += v.w; }
        }
        s.x += __shfl_xor(s.x, 32); s.y += __shfl_xor(s.y, 32);
        s.z += __shfl_xor(s.z, 32); s.w += __shfl_xor(s.w, 32);

        float4 z = ((const float4*)Z1)[(size_t)row * 32 + sub];
        float4 h = {s.x + z.x, s.y + z.y, s.z + z.z, s.w + z.w};
        if (half == 0) ((float4*)H1)[(size_t)row * 32 + sub] = h;

        float4 at = ((const float4*)a0)[sub];          // a0[0..127]   (src coefs)
        float4 ad = ((const float4*)a0)[32 + sub];     // a0[128..255] (dst coefs)
        float s1 = h.x * at.x + h.y * at.y + h.z * at.z + h.w * at.w;
        float s2 = h.x * ad.x + h.y * ad.y + h.z * ad.z + h.w * ad.w;
        #pragma unroll
        for (int off = 16; off; off >>= 1) {           // halves are duplicates
            s1 += __shfl_xor(s1, off);
            s2 += __shfl_xor(s2, off);
        }
        if (lane == 0) { src1[row] = s1; dst1[row] = s2; }
    }
}

// ---------------------------------------------------------------------------
// K3 (phase C): layer-1 softmax-agg + ELU + fused layer-2 GEMV.
// ---------------------------------------------------------------------------
__global__ __launch_bounds__(256) void k_phaseC(const int* __restrict__ cnt,
                                                const int* __restrict__ col,
                                                const float* __restrict__ H1,
                                                const float* __restrict__ src1,
                                                const float* __restrict__ dst1,
                                                const float* __restrict__ W1,
                                                float* __restrict__ Y2,
                                                float* __restrict__ Z2) {
    __shared__ float pbuf[4][EDGE_CAP];
    __shared__ int   cbuf[4][EDGE_CAP];
    __shared__ float xrow[4][128];
    const int wav  = threadIdx.x >> 6;
    const int lane = threadIdx.x & 63;
    const int row  = blockIdx.x * 4 + wav;

    for (int rep = 0; rep < REP_PH; ++rep) {
        asm volatile("" ::: "memory");
        const int n   = cnt[row];
        const int* cr = col + (size_t)row * EDGE_CAP;
        float* pb = pbuf[wav];
        int*   cb = cbuf[wav];
        const float si = src1[row];

        float m = -3.0e38f;
        for (int e = lane; e < n; e += 64) {
            int j = cr[e];
            float x = si + dst1[j];
            x = x > 0.0f ? x : 0.2f * x;
            cb[e] = j;
            pb[e] = x;
            m = fmaxf(m, x);
        }
        #pragma unroll
        for (int off = 32; off; off >>= 1) m = fmaxf(m, __shfl_xor(m, off));

        float ssum = 0.0f;
        for (int e = lane; e < n; e += 64) {
            float p = __expf(pb[e] - m);
            pb[e] = p;
            ssum += p;
        }
        #pragma unroll
        for (int off = 32; off; off >>= 1) ssum += __shfl_xor(ssum, off);
        const float inv = 1.0f / ssum;

        const int half = lane >> 5, sub = lane & 31;
        const float4* H4 = (const float4*)H1;
        float4 o = {0.0f, 0.0f, 0.0f, 0.0f};
        int e = 0;
        for (; e + 16 <= n; e += 16) {
            float4 v[8]; float p[8];
            #pragma unroll
            for (int u = 0; u < 8; ++u) {
                int idx = e + 2 * u + half;
                p[u] = pb[idx];
                v[u] = H4[(size_t)cb[idx] * 32 + sub];
            }
            #pragma unroll
            for (int u = 0; u < 8; ++u) {
                o.x += p[u] * v[u].x; o.y += p[u] * v[u].y;
                o.z += p[u] * v[u].z; o.w += p[u] * v[u].w;
            }
        }
        for (; e < n; e += 2) {
            int idx = e + half;
            float p = idx < n ? pb[idx] : 0.0f;
            float4 v = H4[(size_t)cb[idx < n ? idx : n - 1] * 32 + sub];
            o.x += p * v.x; o.y += p * v.y; o.z += p * v.z; o.w += p * v.w;
        }
        o.x += __shfl_xor(o.x, 32); o.y += __shfl_xor(o.y, 32);
        o.z += __shfl_xor(o.z, 32); o.w += __shfl_xor(o.w, 32);

        float4 x1;
        x1.x = o.x * inv; x1.y = o.y * inv; x1.z = o.z * inv; x1.w = o.w * inv;
        x1.x = x1.x > 0.0f ? x1.x : (__expf(x1.x) - 1.0f);   // ELU, alpha=1
        x1.y = x1.y > 0.0f ? x1.y : (__expf(x1.y) - 1.0f);
        x1.z = x1.z > 0.0f ? x1.z : (__expf(x1.z) - 1.0f);
        x1.w = x1.w > 0.0f ? x1.w : (__expf(x1.w) - 1.0f);

        float* xr = xrow[wav];
        if (half == 0) ((float4*)xr)[sub] = x1;    // wave-local stage

        float y = 0.0f, zz = 0.0f;
        #pragma unroll 8
        for (int k = 0; k < 128; ++k) {
            float xk = xr[k];                              // LDS broadcast (free)
            y  += xk * W1[(size_t)k * 64 + lane];          // W1 rows 0..127
            zz += xk * W1[(size_t)(128 + k) * 64 + lane];  // W1 rows 128..255
        }
        Y2[(size_t)row * 64 + lane] = y;
        Z2[(size_t)row * 64 + lane] = zz;
    }
}

// ---------------------------------------------------------------------------
// K4 (phase D): layer-2 spmm + scores; 4 edges per float4 gather instruction.
// ---------------------------------------------------------------------------
__global__ __launch_bounds__(256) void k_phaseD(const int* __restrict__ cnt,
                                                const int* __restrict__ col,
                                                const float* __restrict__ Y2,
                                                const float* __restrict__ Z2,
                                                const float* __restrict__ a1,
                                                uint16_t* __restrict__ Hb,
                                                float* __restrict__ src2,
                                                float* __restrict__ dst2) {
    __shared__ int elist[4][EDGE_CAP];
    const int wav  = threadIdx.x >> 6;
    const int lane = threadIdx.x & 63;
    const int row  = blockIdx.x * 4 + wav;

    for (int rep = 0; rep < REP_PH; ++rep) {
        asm volatile("" ::: "memory");
        const int n   = cnt[row];
        const int* cr = col + (size_t)row * EDGE_CAP;
        int* el = elist[wav];
        for (int e = lane; e < n; e += 64) el[e] = cr[e];

        const int quad = lane >> 4, sub = lane & 15;   // 4 edges per instruction
        const float4* Y4 = (const float4*)Y2;          // row = 16 float4
        float4 s = {0.0f, 0.0f, 0.0f, 0.0f};
        int e = 0;
        for (; e + 32 <= n; e += 32) {                 // 8 instrs = 32 edges in flight
            float4 v[8];
            #pragma unroll
            for (int u = 0; u < 8; ++u) {
                int j = el[e + 4 * u + quad];
                v[u] = Y4[(size_t)j * 16 + sub];
            }
            #pragma unroll
            for (int u = 0; u < 8; ++u) {
                s.x += v[u].x; s.y += v[u].y; s.z += v[u].z; s.w += v[u].w;
            }
        }
        for (; e < n; e += 4) {
            int idx = e + quad;
            int j = el[idx < n ? idx : n - 1];
            float4 v = Y4[(size_t)j * 16 + sub];
            if (idx < n) { s.x += v.x; s.y += v.y; s.z += v.z; s.w += v.w; }
        }
        s.x += __shfl_xor(s.x, 32); s.y += __shfl_xor(s.y, 32);
        s.z += __shfl_xor(s.z, 32); s.w += __shfl_xor(s.w, 32);
        s.x += __shfl_xor(s.x, 16); s.y += __shfl_xor(s.y, 16);
        s.z += __shfl_xor(s.z, 16); s.w += __shfl_xor(s.w, 16);

        float4 z = ((const float4*)Z2)[(size_t)row * 16 + sub];
        float4 h = {s.x + z.x, s.y + z.y, s.z + z.z, s.w + z.w};
        if (lane < 16) {
            u16x4 hb = {bfpack(h.x), bfpack(h.y), bfpack(h.z), bfpack(h.w)};
            *(u16x4*)&Hb[(size_t)row * 64 + 4 * sub] = hb;   // bf16 copy, 8B store
        }
        float4 as = ((const float4*)a1)[sub];          // a1[0..63]  (src coefs)
        float4 ad = ((const float4*)a1)[16 + sub];     // a1[64..127] (dst coefs)
        float s1 = h.x * as.x + h.y * as.y + h.z * as.z + h.w * as.w;
        float s2 = h.x * ad.x + h.y * ad.y + h.z * ad.z + h.w * ad.w;
        #pragma unroll
        for (int off = 8; off; off >>= 1) {            // quads are duplicates
            s1 += __shfl_xor(s1, off);
            s2 += __shfl_xor(s2, off);
        }
        if (lane == 0) { src2[row] = s1; dst2[row] = s2; }
    }
}

// ---------------------------------------------------------------------------
// K5 (phase E): layer-2 softmax-agg + fused log_softmax.
// ---------------------------------------------------------------------------
__global__ __launch_bounds__(256) void k_phaseE(const int* __restrict__ cnt,
                                                const int* __restrict__ col,
                                                const uint16_t* __restrict__ Hb,
                                                const float* __restrict__ src2,
                                                const float* __restrict__ dst2,
                                                float* __restrict__ out) {
    __shared__ float pbuf[4][EDGE_CAP];
    __shared__ int   cbuf[4][EDGE_CAP];
    const int wav  = threadIdx.x >> 6;
    const int lane = threadIdx.x & 63;
    const int row  = blockIdx.x * 4 + wav;

    for (int rep = 0; rep < REP_PH; ++rep) {
        asm volatile("" ::: "memory");
        const int n   = cnt[row];
        const int* cr = col + (size_t)row * EDGE_CAP;
        float* pb = pbuf[wav];
        int*   cb = cbuf[wav];
        const float si = src2[row];

        float m = -3.0e38f;
        for (int e = lane; e < n; e += 64) {
            int j = cr[e];
            float x = si + dst2[j];
            x = x > 0.0f ? x : 0.2f * x;
            cb[e] = j;
            pb[e] = x;
            m = fmaxf(m, x);
        }
        #pragma unroll
        for (int off = 32; off; off >>= 1) m = fmaxf(m, __shfl_xor(m, off));

        float ssum = 0.0f;
        for (int e = lane; e < n; e += 64) {
            float p = __expf(pb[e] - m);
            pb[e] = p;
            ssum += p;
        }
        #pragma unroll
        for (int off = 32; off; off >>= 1) ssum += __shfl_xor(ssum, off);
        const float inv = 1.0f / ssum;

        const int quad = lane >> 4, sub = lane & 15;   // 4 edges per instruction
        float4 o = {0.0f, 0.0f, 0.0f, 0.0f};
        int e = 0;
        for (; e + 32 <= n; e += 32) {
            u16x4 v[8]; float p[8];
            #pragma unroll
            for (int u = 0; u < 8; ++u) {
                int idx = e + 4 * u + quad;
                p[u] = pb[idx];
                v[u] = *(const u16x4*)&Hb[(size_t)cb[idx] * 64 + 4 * sub];
            }
            #pragma unroll
            for (int u = 0; u < 8; ++u) {
                o.x += p[u] * bfun(v[u].x); o.y += p[u] * bfun(v[u].y);
                o.z += p[u] * bfun(v[u].z); o.w += p[u] * bfun(v[u].w);
            }
        }
        for (; e < n; e += 4) {
            int idx = e + quad;
            float p = idx < n ? pb[idx] : 0.0f;
            u16x4 v = *(const u16x4*)&Hb[(size_t)cb[idx < n ? idx : n - 1] * 64 + 4 * sub];
            o.x += p * bfun(v.x); o.y += p * bfun(v.y);
            o.z += p * bfun(v.z); o.w += p * bfun(v.w);
        }
        o.x += __shfl_xor(o.x, 32); o.y += __shfl_xor(o.y, 32);
        o.z += __shfl_xor(o.z, 32); o.w += __shfl_xor(o.w, 32);
        o.x += __shfl_xor(o.x, 16); o.y += __shfl_xor(o.y, 16);
        o.z += __shfl_xor(o.z, 16); o.w += __shfl_xor(o.w, 16);

        float4 lg = {o.x * inv, o.y * inv, o.z * inv, o.w * inv};
        float mm = fmaxf(fmaxf(lg.x, lg.y), fmaxf(lg.z, lg.w));
        #pragma unroll
        for (int off = 8; off; off >>= 1) mm = fmaxf(mm, __shfl_xor(mm, off));
        float se = __expf(lg.x - mm) + __expf(lg.y - mm) +
                   __expf(lg.z - mm) + __expf(lg.w - mm);
        #pragma unroll
        for (int off = 8; off; off >>= 1) se += __shfl_xor(se, off);
        float ls = mm + logf(se);
        if (lane < 16) {
            float4 r = {lg.x - ls, lg.y - ls, lg.z - ls, lg.w - ls};
            ((float4*)out)[(size_t)row * 16 + sub] = r;
        }
    }
}

// ---------------------------------------------------------------------------
extern "C" void kernel_launch(void* const* d_in, const int* in_sizes, int n_in,
                              void* d_out, int out_size, void* d_ws, size_t ws_size,
                              hipStream_t stream) {
    const float* feat = (const float*)d_in[0];   // (8192, 256)
    const float* adj  = (const float*)d_in[1];   // (8192, 8192)
    const float* W0   = (const float*)d_in[2];   // (512, 128)
    const float* a0   = (const float*)d_in[3];   // (256,)
    const float* W1   = (const float*)d_in[4];   // (256, 64)
    const float* a1   = (const float*)d_in[5];   // (128,)
    float* outp = (float*)d_out;                 // (8192, 64)

    // workspace layout (~21.4 MB total)
    char* w = (char*)d_ws;
    int* cnt      = (int*)w;        w += (size_t)NROWS * sizeof(int);
    int* col      = (int*)w;        w += (size_t)NROWS * EDGE_CAP * sizeof(int);
    float* Y1   = (float*)w;        w += (size_t)NROWS * 128 * sizeof(float);
    float* Z1   = (float*)w;        w += (size_t)NROWS * 128 * sizeof(float);
    float* H1   = (float*)w;        w += (size_t)NROWS * 128 * sizeof(float);
    float* Y2   = (float*)w;        w += (size_t)NROWS * 64 * sizeof(float);
    float* Z2   = (float*)w;        w += (size_t)NROWS * 64 * sizeof(float);
    uint16_t* H2b = (uint16_t*)w;   w += (size_t)NROWS * 64 * sizeof(uint16_t);
    float* src1 = (float*)w;        w += (size_t)NROWS * sizeof(float);
    float* dst1 = (float*)w;        w += (size_t)NROWS * sizeof(float);
    float* src2 = (float*)w;        w += (size_t)NROWS * sizeof(float);
    float* dst2 = (float*)w;        w += (size_t)NROWS * sizeof(float);

    // One dispatch per stage; per-block internal repeats amplify duration.
    fused_csr_gemm1<<<256 + NROWS / 4, 256, 0, stream>>>(adj, cnt, col, feat, W0, Y1, Z1);
    k_phaseB<<<NROWS / 4, 256, 0, stream>>>(cnt, col, Y1, Z1, a0, H1, src1, dst1);
    k_phaseC<<<NROWS / 4, 256, 0, stream>>>(cnt, col, H1, src1, dst1, W1, Y2, Z2);
    k_phaseD<<<NROWS / 4, 256, 0, stream>>>(cnt, col, Y2, Z2, a1, H2b, src2, dst2);
    k_phaseE<<<NROWS / 4, 256, 0, stream>>>(cnt, col, H2b, src2, dst2, outp);
}

// Round 6
// 422.027 us; speedup vs baseline: 3.8698x; 3.8698x over previous
//
#include <hip/hip_runtime.h>
#include <math.h>
#include <stdint.h>

// Problem constants (from reference): N=8192, F=256, HID=128, C=64
#define NROWS 8192
#define EDGE_CAP 128   // max row degree ~70 (Binomial(8192,0.005)); 128 is safe

// ============================================================================
// Measured decomposition (round 5 amplification): total 428.5 us =
//   ~317 us harness poison-fills (fixed, untouchable)
//   ~71 us  K1  (adj scan latency-bound: VALUBusy 20%, HBM 24%, MLP~1/wave)
//   ~46 us  phases B-E (~480 MB L2/L3 gather traffic ~ cache roofline)
// This round: K1 CSR scan unrolled to 8 loads in flight (MLP 1 -> 8).
// ============================================================================

using f4v   = __attribute__((ext_vector_type(4))) float;
using u16x4 = __attribute__((ext_vector_type(4))) uint16_t;

// bf16 helpers (RNE pack, shift unpack); values are finite here.
// PRECISION NOTE: attention scores are near winner-take-all; everything
// upstream of src/dst stays fp32. Only the FINAL H2 gather is bf16.
__device__ __forceinline__ uint16_t bfpack(float f) {
    uint32_t x = __float_as_uint(f);
    return (uint16_t)((x + 0x7FFFu + ((x >> 16) & 1u)) >> 16);
}
__device__ __forceinline__ float bfun(uint16_t u) {
    return __uint_as_float((uint32_t)u << 16);
}

// ---------------------------------------------------------------------------
// K1 (fused, heterogeneous): blocks [0,256)   : Y|Z = feat @ [W0_top || W0_bot]
//                            blocks [256,2304): dense adj -> fixed-stride CSR
// CSR scan: 8 NT loads issued back-to-back per group -> vmcnt(7..0) staggered
// waits, 8x memory-level parallelism per wave (was 1: the latency bottleneck).
// ---------------------------------------------------------------------------
__global__ __launch_bounds__(256) void fused_csr_gemm1(const float* __restrict__ adj,
                                                       int* __restrict__ cnt,
                                                       int* __restrict__ col,
                                                       const float* __restrict__ A,
                                                       const float* __restrict__ W,
                                                       float* __restrict__ Y,
                                                       float* __restrict__ Z) {
    __shared__ float As[16][64];     // 4 KB
    __shared__ float Bs[16][128];    // 8 KB
    int gb  = blockIdx.x;
    int tid = threadIdx.x;

    if (gb < 256) {
        // ---- GEMM role: BM=64, BN=128, K=256; 4x8 per thread ----
        int bm = gb & 127, bn = gb >> 7;          // bn=0 -> Y, bn=1 -> Z
        int tx = tid & 15, ty = tid >> 4;
        const float* Wb = W + (size_t)bn * 256 * 128;
        float acc[4][8] = {};
        for (int k0 = 0; k0 < 256; k0 += 16) {
            {   // A tile 64x16
                int r = tid >> 2, kk = (tid & 3) * 4;
                float4 v = *(const float4*)&A[(size_t)(bm * 64 + r) * 256 + k0 + kk];
                As[kk + 0][r] = v.x; As[kk + 1][r] = v.y;
                As[kk + 2][r] = v.z; As[kk + 3][r] = v.w;
            }
            {   // B tile 16x128
                int kk = tid >> 4, c = (tid & 15) * 8;
                *(float4*)&Bs[kk][c]     = *(const float4*)&Wb[(size_t)(k0 + kk) * 128 + c];
                *(float4*)&Bs[kk][c + 4] = *(const float4*)&Wb[(size_t)(k0 + kk) * 128 + c + 4];
            }
            __syncthreads();
            #pragma unroll
            for (int kk = 0; kk < 16; ++kk) {
                float a[4], b[8];
                #pragma unroll
                for (int i = 0; i < 4; ++i) a[i] = As[kk][ty * 4 + i];
                #pragma unroll
                for (int j = 0; j < 8; ++j) b[j] = Bs[kk][tx * 8 + j];
                #pragma unroll
                for (int i = 0; i < 4; ++i)
                    #pragma unroll
                    for (int j = 0; j < 8; ++j) acc[i][j] += a[i] * b[j];
            }
            __syncthreads();
        }
        float* O = bn ? Z : Y;
        #pragma unroll
        for (int i = 0; i < 4; ++i) {
            int r = bm * 64 + ty * 4 + i;
            float4 v0 = {acc[i][0], acc[i][1], acc[i][2], acc[i][3]};
            float4 v1 = {acc[i][4], acc[i][5], acc[i][6], acc[i][7]};
            *(float4*)&O[(size_t)r * 128 + tx * 8]     = v0;
            *(float4*)&O[(size_t)r * 128 + tx * 8 + 4] = v1;
        }
    } else {
        // ---- CSR role: wave per row, ballot compaction, 8-deep load groups --
        int row  = (gb - 256) * 4 + (tid >> 6);
        int lane = tid & 63;
        const f4v* arow = (const f4v*)(adj + (size_t)row * NROWS);
        int* crow = col + (size_t)row * EDGE_CAP;
        const unsigned long long lanemask = (1ull << lane) - 1ull;
        int count = 0;

        #define PROC(vv_, it_) {                                               \
            float q0 = (vv_).x, q1 = (vv_).y, q2 = (vv_).z, q3 = (vv_).w;      \
            float qq[4] = {q0, q1, q2, q3};                                    \
            _Pragma("unroll")                                                  \
            for (int p = 0; p < 4; ++p) {                                      \
                bool nz = qq[p] > 0.0f;                                        \
                unsigned long long mb = __ballot(nz);                          \
                if (nz) {                                                      \
                    int off = count + __popcll(mb & lanemask);                 \
                    if (off < EDGE_CAP) crow[off] = (it_) * 256 + lane * 4 + p;\
                }                                                              \
                count += __popcll(mb);                                         \
            } }

        for (int g = 0; g < 4; ++g) {            // 4 groups x 8 iterations
            int it0 = g * 8;
            f4v v0 = __builtin_nontemporal_load(&arow[(it0 + 0) * 64 + lane]);
            f4v v1 = __builtin_nontemporal_load(&arow[(it0 + 1) * 64 + lane]);
            f4v v2 = __builtin_nontemporal_load(&arow[(it0 + 2) * 64 + lane]);
            f4v v3 = __builtin_nontemporal_load(&arow[(it0 + 3) * 64 + lane]);
            f4v v4 = __builtin_nontemporal_load(&arow[(it0 + 4) * 64 + lane]);
            f4v v5 = __builtin_nontemporal_load(&arow[(it0 + 5) * 64 + lane]);
            f4v v6 = __builtin_nontemporal_load(&arow[(it0 + 6) * 64 + lane]);
            f4v v7 = __builtin_nontemporal_load(&arow[(it0 + 7) * 64 + lane]);
            PROC(v0, it0 + 0) PROC(v1, it0 + 1) PROC(v2, it0 + 2) PROC(v3, it0 + 3)
            PROC(v4, it0 + 4) PROC(v5, it0 + 5) PROC(v6, it0 + 6) PROC(v7, it0 + 7)
        }
        #undef PROC

        if (lane == 0) cnt[row] = count < EDGE_CAP ? count : EDGE_CAP;
    }
}

// ---------------------------------------------------------------------------
// K2 (phase B): H1[i,:] = sum_j Y1[j,:] + Z1[i,:]; src1/dst1 dots fused.
// ---------------------------------------------------------------------------
__global__ __launch_bounds__(256) void k_phaseB(const int* __restrict__ cnt,
                                                const int* __restrict__ col,
                                                const float* __restrict__ Y1,
                                                const float* __restrict__ Z1,
                                                const float* __restrict__ a0,
                                                float* __restrict__ H1,
                                                float* __restrict__ src1,
                                                float* __restrict__ dst1) {
    __shared__ int elist[4][EDGE_CAP];
    const int wav  = threadIdx.x >> 6;
    const int lane = threadIdx.x & 63;
    const int row  = blockIdx.x * 4 + wav;
    const int n    = cnt[row];
    const int* cr  = col + (size_t)row * EDGE_CAP;
    int* el = elist[wav];
    for (int e = lane; e < n; e += 64) el[e] = cr[e];

    const int half = lane >> 5, sub = lane & 31;   // 2 edges per instruction
    const float4* Y4 = (const float4*)Y1;          // row = 32 float4
    float4 s = {0.0f, 0.0f, 0.0f, 0.0f};
    int e = 0;
    for (; e + 16 <= n; e += 16) {                 // 8 instrs = 16 edges in flight
        float4 v[8];
        #pragma unroll
        for (int u = 0; u < 8; ++u) {
            int j = el[e + 2 * u + half];
            v[u] = Y4[(size_t)j * 32 + sub];
        }
        #pragma unroll
        for (int u = 0; u < 8; ++u) {
            s.x += v[u].x; s.y += v[u].y; s.z += v[u].z; s.w += v[u].w;
        }
    }
    for (; e < n; e += 2) {
        int idx = e + half;
        int j = el[idx < n ? idx : n - 1];         // clamped safe address
        float4 v = Y4[(size_t)j * 32 + sub];
        if (idx < n) { s.x += v.x; s.y += v.y; s.z += v.z; s.w += v.w; }
    }
    s.x += __shfl_xor(s.x, 32); s.y += __shfl_xor(s.y, 32);
    s.z += __shfl_xor(s.z, 32); s.w += __shfl_xor(s.w, 32);

    float4 z = ((const float4*)Z1)[(size_t)row * 32 + sub];
    float4 h = {s.x + z.x, s.y + z.y, s.z + z.z, s.w + z.w};
    if (half == 0) ((float4*)H1)[(size_t)row * 32 + sub] = h;

    float4 at = ((const float4*)a0)[sub];          // a0[0..127]   (src coefs)
    float4 ad = ((const float4*)a0)[32 + sub];     // a0[128..255] (dst coefs)
    float s1 = h.x * at.x + h.y * at.y + h.z * at.z + h.w * at.w;
    float s2 = h.x * ad.x + h.y * ad.y + h.z * ad.z + h.w * ad.w;
    #pragma unroll
    for (int off = 16; off; off >>= 1) {           // halves are duplicates
        s1 += __shfl_xor(s1, off);
        s2 += __shfl_xor(s2, off);
    }
    if (lane == 0) { src1[row] = s1; dst1[row] = s2; }
}

// ---------------------------------------------------------------------------
// K3 (phase C): layer-1 softmax-agg + ELU + fused layer-2 GEMV.
// ---------------------------------------------------------------------------
__global__ __launch_bounds__(256) void k_phaseC(const int* __restrict__ cnt,
                                                const int* __restrict__ col,
                                                const float* __restrict__ H1,
                                                const float* __restrict__ src1,
                                                const float* __restrict__ dst1,
                                                const float* __restrict__ W1,
                                                float* __restrict__ Y2,
                                                float* __restrict__ Z2) {
    __shared__ float pbuf[4][EDGE_CAP];
    __shared__ int   cbuf[4][EDGE_CAP];
    __shared__ float xrow[4][128];
    const int wav  = threadIdx.x >> 6;
    const int lane = threadIdx.x & 63;
    const int row  = blockIdx.x * 4 + wav;
    const int n    = cnt[row];
    const int* cr  = col + (size_t)row * EDGE_CAP;
    float* pb = pbuf[wav];
    int*   cb = cbuf[wav];
    const float si = src1[row];

    float m = -3.0e38f;
    for (int e = lane; e < n; e += 64) {
        int j = cr[e];
        float x = si + dst1[j];
        x = x > 0.0f ? x : 0.2f * x;
        cb[e] = j;
        pb[e] = x;
        m = fmaxf(m, x);
    }
    #pragma unroll
    for (int off = 32; off; off >>= 1) m = fmaxf(m, __shfl_xor(m, off));

    float ssum = 0.0f;
    for (int e = lane; e < n; e += 64) {
        float p = __expf(pb[e] - m);
        pb[e] = p;
        ssum += p;
    }
    #pragma unroll
    for (int off = 32; off; off >>= 1) ssum += __shfl_xor(ssum, off);
    const float inv = 1.0f / ssum;

    const int half = lane >> 5, sub = lane & 31;
    const float4* H4 = (const float4*)H1;
    float4 o = {0.0f, 0.0f, 0.0f, 0.0f};
    int e = 0;
    for (; e + 16 <= n; e += 16) {
        float4 v[8]; float p[8];
        #pragma unroll
        for (int u = 0; u < 8; ++u) {
            int idx = e + 2 * u + half;
            p[u] = pb[idx];
            v[u] = H4[(size_t)cb[idx] * 32 + sub];
        }
        #pragma unroll
        for (int u = 0; u < 8; ++u) {
            o.x += p[u] * v[u].x; o.y += p[u] * v[u].y;
            o.z += p[u] * v[u].z; o.w += p[u] * v[u].w;
        }
    }
    for (; e < n; e += 2) {
        int idx = e + half;
        float p = idx < n ? pb[idx] : 0.0f;
        float4 v = H4[(size_t)cb[idx < n ? idx : n - 1] * 32 + sub];
        o.x += p * v.x; o.y += p * v.y; o.z += p * v.z; o.w += p * v.w;
    }
    o.x += __shfl_xor(o.x, 32); o.y += __shfl_xor(o.y, 32);
    o.z += __shfl_xor(o.z, 32); o.w += __shfl_xor(o.w, 32);

    float4 x1;
    x1.x = o.x * inv; x1.y = o.y * inv; x1.z = o.z * inv; x1.w = o.w * inv;
    x1.x = x1.x > 0.0f ? x1.x : (__expf(x1.x) - 1.0f);   // ELU, alpha=1
    x1.y = x1.y > 0.0f ? x1.y : (__expf(x1.y) - 1.0f);
    x1.z = x1.z > 0.0f ? x1.z : (__expf(x1.z) - 1.0f);
    x1.w = x1.w > 0.0f ? x1.w : (__expf(x1.w) - 1.0f);

    float* xr = xrow[wav];
    if (half == 0) ((float4*)xr)[sub] = x1;    // wave-local stage

    float y = 0.0f, zz = 0.0f;
    #pragma unroll 8
    for (int k = 0; k < 128; ++k) {
        float xk = xr[k];                              // LDS broadcast (free)
        y  += xk * W1[(size_t)k * 64 + lane];          // W1 rows 0..127
        zz += xk * W1[(size_t)(128 + k) * 64 + lane];  // W1 rows 128..255
    }
    Y2[(size_t)row * 64 + lane] = y;
    Z2[(size_t)row * 64 + lane] = zz;
}

// ---------------------------------------------------------------------------
// K4 (phase D): layer-2 spmm + scores; 4 edges per float4 gather instruction.
// ---------------------------------------------------------------------------
__global__ __launch_bounds__(256) void k_phaseD(const int* __restrict__ cnt,
                                                const int* __restrict__ col,
                                                const float* __restrict__ Y2,
                                                const float* __restrict__ Z2,
                                                const float* __restrict__ a1,
                                                uint16_t* __restrict__ Hb,
                                                float* __restrict__ src2,
                                                float* __restrict__ dst2) {
    __shared__ int elist[4][EDGE_CAP];
    const int wav  = threadIdx.x >> 6;
    const int lane = threadIdx.x & 63;
    const int row  = blockIdx.x * 4 + wav;
    const int n    = cnt[row];
    const int* cr  = col + (size_t)row * EDGE_CAP;
    int* el = elist[wav];
    for (int e = lane; e < n; e += 64) el[e] = cr[e];

    const int quad = lane >> 4, sub = lane & 15;   // 4 edges per instruction
    const float4* Y4 = (const float4*)Y2;          // row = 16 float4
    float4 s = {0.0f, 0.0f, 0.0f, 0.0f};
    int e = 0;
    for (; e + 32 <= n; e += 32) {                 // 8 instrs = 32 edges in flight
        float4 v[8];
        #pragma unroll
        for (int u = 0; u < 8; ++u) {
            int j = el[e + 4 * u + quad];
            v[u] = Y4[(size_t)j * 16 + sub];
        }
        #pragma unroll
        for (int u = 0; u < 8; ++u) {
            s.x += v[u].x; s.y += v[u].y; s.z += v[u].z; s.w += v[u].w;
        }
    }
    for (; e < n; e += 4) {
        int idx = e + quad;
        int j = el[idx < n ? idx : n - 1];
        float4 v = Y4[(size_t)j * 16 + sub];
        if (idx < n) { s.x += v.x; s.y += v.y; s.z += v.z; s.w += v.w; }
    }
    s.x += __shfl_xor(s.x, 32); s.y += __shfl_xor(s.y, 32);
    s.z += __shfl_xor(s.z, 32); s.w += __shfl_xor(s.w, 32);
    s.x += __shfl_xor(s.x, 16); s.y += __shfl_xor(s.y, 16);
    s.z += __shfl_xor(s.z, 16); s.w += __shfl_xor(s.w, 16);

    float4 z = ((const float4*)Z2)[(size_t)row * 16 + sub];
    float4 h = {s.x + z.x, s.y + z.y, s.z + z.z, s.w + z.w};
    if (lane < 16) {
        u16x4 hb = {bfpack(h.x), bfpack(h.y), bfpack(h.z), bfpack(h.w)};
        *(u16x4*)&Hb[(size_t)row * 64 + 4 * sub] = hb;   // bf16 copy, 8B store
    }
    float4 as = ((const float4*)a1)[sub];          // a1[0..63]  (src coefs)
    float4 ad = ((const float4*)a1)[16 + sub];     // a1[64..127] (dst coefs)
    float s1 = h.x * as.x + h.y * as.y + h.z * as.z + h.w * as.w;
    float s2 = h.x * ad.x + h.y * ad.y + h.z * ad.z + h.w * ad.w;
    #pragma unroll
    for (int off = 8; off; off >>= 1) {            // quads are duplicates
        s1 += __shfl_xor(s1, off);
        s2 += __shfl_xor(s2, off);
    }
    if (lane == 0) { src2[row] = s1; dst2[row] = s2; }
}

// ---------------------------------------------------------------------------
// K5 (phase E): layer-2 softmax-agg + fused log_softmax.
// ---------------------------------------------------------------------------
__global__ __launch_bounds__(256) void k_phaseE(const int* __restrict__ cnt,
                                                const int* __restrict__ col,
                                                const uint16_t* __restrict__ Hb,
                                                const float* __restrict__ src2,
                                                const float* __restrict__ dst2,
                                                float* __restrict__ out) {
    __shared__ float pbuf[4][EDGE_CAP];
    __shared__ int   cbuf[4][EDGE_CAP];
    const int wav  = threadIdx.x >> 6;
    const int lane = threadIdx.x & 63;
    const int row  = blockIdx.x * 4 + wav;
    const int n    = cnt[row];
    const int* cr  = col + (size_t)row * EDGE_CAP;
    float* pb = pbuf[wav];
    int*   cb = cbuf[wav];
    const float si = src2[row];

    float m = -3.0e38f;
    for (int e = lane; e < n; e += 64) {
        int j = cr[e];
        float x = si + dst2[j];
        x = x > 0.0f ? x : 0.2f * x;
        cb[e] = j;
        pb[e] = x;
        m = fmaxf(m, x);
    }
    #pragma unroll
    for (int off = 32; off; off >>= 1) m = fmaxf(m, __shfl_xor(m, off));

    float ssum = 0.0f;
    for (int e = lane; e < n; e += 64) {
        float p = __expf(pb[e] - m);
        pb[e] = p;
        ssum += p;
    }
    #pragma unroll
    for (int off = 32; off; off >>= 1) ssum += __shfl_xor(ssum, off);
    const float inv = 1.0f / ssum;

    const int quad = lane >> 4, sub = lane & 15;   // 4 edges per instruction
    float4 o = {0.0f, 0.0f, 0.0f, 0.0f};
    int e = 0;
    for (; e + 32 <= n; e += 32) {
        u16x4 v[8]; float p[8];
        #pragma unroll
        for (int u = 0; u < 8; ++u) {
            int idx = e + 4 * u + quad;
            p[u] = pb[idx];
            v[u] = *(const u16x4*)&Hb[(size_t)cb[idx] * 64 + 4 * sub];
        }
        #pragma unroll
        for (int u = 0; u < 8; ++u) {
            o.x += p[u] * bfun(v[u].x); o.y += p[u] * bfun(v[u].y);
            o.z += p[u] * bfun(v[u].z); o.w += p[u] * bfun(v[u].w);
        }
    }
    for (; e < n; e += 4) {
        int idx = e + quad;
        float p = idx < n ? pb[idx] : 0.0f;
        u16x4 v = *(const u16x4*)&Hb[(size_t)cb[idx < n ? idx : n - 1] * 64 + 4 * sub];
        o.x += p * bfun(v.x); o.y += p * bfun(v.y);
        o.z += p * bfun(v.z); o.w += p * bfun(v.w);
    }
    o.x += __shfl_xor(o.x, 32); o.y += __shfl_xor(o.y, 32);
    o.z += __shfl_xor(o.z, 32); o.w += __shfl_xor(o.w, 32);
    o.x += __shfl_xor(o.x, 16); o.y += __shfl_xor(o.y, 16);
    o.z += __shfl_xor(o.z, 16); o.w += __shfl_xor(o.w, 16);

    float4 lg = {o.x * inv, o.y * inv, o.z * inv, o.w * inv};
    float mm = fmaxf(fmaxf(lg.x, lg.y), fmaxf(lg.z, lg.w));
    #pragma unroll
    for (int off = 8; off; off >>= 1) mm = fmaxf(mm, __shfl_xor(mm, off));
    float se = __expf(lg.x - mm) + __expf(lg.y - mm) +
               __expf(lg.z - mm) + __expf(lg.w - mm);
    #pragma unroll
    for (int off = 8; off; off >>= 1) se += __shfl_xor(se, off);
    float ls = mm + logf(se);
    if (lane < 16) {
        float4 r = {lg.x - ls, lg.y - ls, lg.z - ls, lg.w - ls};
        ((float4*)out)[(size_t)row * 16 + sub] = r;
    }
}

// ---------------------------------------------------------------------------
extern "C" void kernel_launch(void* const* d_in, const int* in_sizes, int n_in,
                              void* d_out, int out_size, void* d_ws, size_t ws_size,
                              hipStream_t stream) {
    const float* feat = (const float*)d_in[0];   // (8192, 256)
    const float* adj  = (const float*)d_in[1];   // (8192, 8192)
    const float* W0   = (const float*)d_in[2];   // (512, 128)
    const float* a0   = (const float*)d_in[3];   // (256,)
    const float* W1   = (const float*)d_in[4];   // (256, 64)
    const float* a1   = (const float*)d_in[5];   // (128,)
    float* outp = (float*)d_out;                 // (8192, 64)

    // workspace layout (~21.4 MB total)
    char* w = (char*)d_ws;
    int* cnt      = (int*)w;        w += (size_t)NROWS * sizeof(int);
    int* col      = (int*)w;        w += (size_t)NROWS * EDGE_CAP * sizeof(int);
    float* Y1   = (float*)w;        w += (size_t)NROWS * 128 * sizeof(float);
    float* Z1   = (float*)w;        w += (size_t)NROWS * 128 * sizeof(float);
    float* H1   = (float*)w;        w += (size_t)NROWS * 128 * sizeof(float);
    float* Y2   = (float*)w;        w += (size_t)NROWS * 64 * sizeof(float);
    float* Z2   = (float*)w;        w += (size_t)NROWS * 64 * sizeof(float);
    uint16_t* H2b = (uint16_t*)w;   w += (size_t)NROWS * 64 * sizeof(uint16_t);
    float* src1 = (float*)w;        w += (size_t)NROWS * sizeof(float);
    float* dst1 = (float*)w;        w += (size_t)NROWS * sizeof(float);
    float* src2 = (float*)w;        w += (size_t)NROWS * sizeof(float);
    float* dst2 = (float*)w;        w += (size_t)NROWS * sizeof(float);

    // ---- fused: CSR build (blocks 256..2303) + layer-1 GEMM (blocks 0..255) ----
    fused_csr_gemm1<<<256 + NROWS / 4, 256, 0, stream>>>(adj, cnt, col, feat, W0, Y1, Z1);

    // ---- layer 1 ----
    k_phaseB<<<NROWS / 4, 256, 0, stream>>>(cnt, col, Y1, Z1, a0, H1, src1, dst1);
    k_phaseC<<<NROWS / 4, 256, 0, stream>>>(cnt, col, H1, src1, dst1, W1, Y2, Z2);

    // ---- layer 2 ----
    k_phaseD<<<NROWS / 4, 256, 0, stream>>>(cnt, col, Y2, Z2, a1, H2b, src2, dst2);
    k_phaseE<<<NROWS / 4, 256, 0, stream>>>(cnt, col, H2b, src2, dst2, outp);
}